// Round 8
// baseline (971.758 us; speedup 1.0000x reference)
//
#include <hip/hip_runtime.h>
#include <hip/hip_bf16.h>
#include <cmath>

#define N_NODES 50000
#define N_EDGES 800000
#define NODE_DIM 128
#define EDGE_DIM 100
#define EMB_DIM 92
#define N_GRAPHS 256

typedef __attribute__((ext_vector_type(8))) short short8_t;
typedef __attribute__((ext_vector_type(4))) float float4_t;

__device__ __forceinline__ float softplus_f(float v) {
    return v > 20.0f ? v : __logf(1.0f + __expf(v));
}
__device__ __forceinline__ float sigmoid_f(float v) {
    return 1.0f / (1.0f + __expf(-v));
}

// ---------------------------------------------------------------- CSR build
__global__ void deg_kernel(const int* __restrict__ ei, int* __restrict__ deg) {
    int e = blockIdx.x * blockDim.x + threadIdx.x;
    if (e >= N_EDGES) return;
    atomicAdd(&deg[ei[N_EDGES + e]], 1);
}

#define SB 1024
__global__ void scan1_kernel(const int* __restrict__ deg, int* __restrict__ rp,
                             int* __restrict__ bsum) {
    __shared__ int buf[SB];
    int b = blockIdx.x, t = threadIdx.x, i = b * SB + t;
    int v = (i < N_NODES) ? deg[i] : 0;
    buf[t] = v;
    __syncthreads();
    for (int off = 1; off < SB; off <<= 1) {
        int a = (t >= off) ? buf[t - off] : 0;
        __syncthreads();
        buf[t] += a;
        __syncthreads();
    }
    if (i < N_NODES) rp[i] = buf[t] - v;
    if (t == SB - 1) bsum[b] = buf[t];
}
__global__ void scan2_kernel(int* __restrict__ bsum, int n) {
    if (threadIdx.x == 0) {
        int s = 0;
        for (int i = 0; i < n; i++) { int v = bsum[i]; bsum[i] = s; s += v; }
    }
}
__global__ void scan3_kernel(int* __restrict__ rp, const int* __restrict__ bsum) {
    int i = blockIdx.x * SB + threadIdx.x;
    if (i < N_NODES) rp[i] += bsum[blockIdx.x];
    if (i == 0) rp[N_NODES] = N_EDGES;
}

__global__ void fill_kernel(const int* __restrict__ ei, const float* __restrict__ R,
                            const int* __restrict__ row_ptr, int* __restrict__ cnt2,
                            int* __restrict__ s_src, float* __restrict__ s_d) {
    int e = blockIdx.x * blockDim.x + threadIdx.x;
    if (e >= N_EDGES) return;
    int s = ei[e];
    int dst = ei[N_EDGES + e];
    float dx = R[3 * s + 0] - R[3 * dst + 0];
    float dy = R[3 * s + 1] - R[3 * dst + 1];
    float dz = R[3 * s + 2] - R[3 * dst + 2];
    float d = sqrtf(dx * dx + dy * dy + dz * dz);
    int pos = row_ptr[dst] + atomicAdd(&cnt2[dst], 1);
    s_src[pos] = s;
    s_d[pos] = d;
}

// ---------------------------------------------------------------- graph boundaries
__global__ void gb_kernel(const int* __restrict__ batch, int* __restrict__ gs) {
    int i = blockIdx.x * 256 + threadIdx.x;
    if (i > N_NODES) return;
    int b = (i < N_NODES) ? batch[i] : N_GRAPHS;
    int pb = (i == 0) ? -1 : batch[i - 1];
    for (int g = pb + 1; g <= b; g++) gs[g] = i;
}

// ---------------------------------------------------------------- We -> bf16 (edge part)
__global__ void wcvt_kernel(const float* __restrict__ conv_w, __hip_bfloat16* __restrict__ Webf) {
    int i = blockIdx.x * 256 + threadIdx.x;
    if (i >= 3 * EDGE_DIM * 256) return;
    int l = i / (EDGE_DIM * 256), r = i - l * (EDGE_DIM * 256);
    Webf[i] = (__hip_bfloat16)conv_w[(size_t)l * 356 * 256 + 256 * 256 + r];
}

// ---------------------------------------------------------------- W1|W2 -> MFMA B-fragment layout
__global__ void wprep_kernel(const float* __restrict__ conv_w, short* __restrict__ WbB) {
    int idx = blockIdx.x * 256 + threadIdx.x;
    if (idx >= 3 * 4 * 32 * 64 * 8) return;
    int j = idx & 7;
    int lane = (idx >> 3) & 63;
    int nt = (idx >> 9) & 31;
    int kc = (idx >> 14) & 3;
    int l = idx >> 16;
    int k = kc * 32 + (lane >> 4) * 8 + j;
    int nl = lane & 15;
    int row, col;
    if (nt < 16) { row = k; col = nt * 16 + nl; }
    else { row = 128 + k; col = (nt - 16) * 16 + nl; }
    __hip_bfloat16 bv = (__hip_bfloat16)conv_w[(size_t)l * 356 * 256 + (size_t)row * 256 + col];
    WbB[idx] = *(short*)&bv;
}

// ---------------------------------------------------------------- embedding (writes x fp32 + xb bf16)
__global__ void embed_kernel(const int* __restrict__ z, const float* __restrict__ emb,
                             const float* __restrict__ emb_w, const float* __restrict__ emb_b,
                             float* __restrict__ x, __hip_bfloat16* __restrict__ xb) {
    __shared__ float er[EMB_DIM * 8];
    __shared__ int zi[8];
    int base = blockIdx.x * 8;
    int t = threadIdx.x;  // 0..127
    if (t < 8) zi[t] = z[base + t];
    __syncthreads();
    for (int idx = t; idx < EMB_DIM * 8; idx += 128) {
        int k = idx >> 3, j = idx & 7;
        er[idx] = emb[zi[j] * EMB_DIM + k];
    }
    __syncthreads();
    float acc[8];
    float bb = emb_b[t];
#pragma unroll
    for (int j = 0; j < 8; j++) acc[j] = bb;
    for (int k = 0; k < EMB_DIM; k++) {
        float w = emb_w[k * NODE_DIM + t];
        float4 ja = *(const float4*)&er[k * 8];
        float4 jb = *(const float4*)&er[k * 8 + 4];
        acc[0] = fmaf(w, ja.x, acc[0]); acc[1] = fmaf(w, ja.y, acc[1]);
        acc[2] = fmaf(w, ja.z, acc[2]); acc[3] = fmaf(w, ja.w, acc[3]);
        acc[4] = fmaf(w, jb.x, acc[4]); acc[5] = fmaf(w, jb.y, acc[5]);
        acc[6] = fmaf(w, jb.z, acc[6]); acc[7] = fmaf(w, jb.w, acc[7]);
    }
#pragma unroll
    for (int j = 0; j < 8; j++) {
        x[(base + j) * NODE_DIM + t] = acc[j];
        xb[(base + j) * NODE_DIM + t] = (__hip_bfloat16)acc[j];
    }
}

// ---------------------------------------------------------------- node GEMM via MFMA
__global__ __launch_bounds__(256) void node_mfma_kernel(
    const __hip_bfloat16* __restrict__ xb, const short* __restrict__ WbB,
    const float* __restrict__ bl, float* __restrict__ P1, float* __restrict__ P2) {
    int t = threadIdx.x;
    int wv = t >> 6, lane = t & 63;
    int mrow = lane & 15, q = lane >> 4;
    int base = blockIdx.x * 16;
    const short* xr = (const short*)xb + (size_t)(base + mrow) * 128 + q * 8;
    float4_t acc[8];
#pragma unroll
    for (int i = 0; i < 8; i++) acc[i] = (float4_t){0.f, 0.f, 0.f, 0.f};
#pragma unroll
    for (int kc = 0; kc < 4; kc++) {
        short8_t a = *(const short8_t*)(xr + kc * 32);
#pragma unroll
        for (int i = 0; i < 8; i++) {
            int nt = wv * 8 + i;
            short8_t b = *(const short8_t*)&WbB[((size_t)(kc * 32 + nt) * 64 + lane) * 8];
            acc[i] = __builtin_amdgcn_mfma_f32_16x16x32_bf16(a, b, acc[i], 0, 0, 0);
        }
    }
    // D layout: col = lane&15, row = (lane>>4)*4 + reg
#pragma unroll
    for (int i = 0; i < 8; i++) {
        int nt = wv * 8 + i;
        int np = nt * 16 + mrow;
        if (np < 256) {
            float bb = bl[np];
#pragma unroll
            for (int r = 0; r < 4; r++)
                P1[(size_t)(base + q * 4 + r) * 256 + np] = acc[i][r] + bb;
        } else {
#pragma unroll
            for (int r = 0; r < 4; r++)
                P2[(size_t)(base + q * 4 + r) * 256 + (np - 256)] = acc[i][r];
        }
    }
}

// ---------------------------------------------------------------- edge msg v15b: batch-4 x 3-set rotation
// (v15 failed to compile: macro args are counted before expansion, so passing a
// 12-token macro as one arg broke. v15b uses token-pasting macros instead.)
// Theory unchanged: v14 showed ~330 cy/edge-wave = ~87 VALU + ~240 memory stall;
// outstanding gathers/thread is the scaling knob. Three named register sets
// (A,B,C) rotate: compute batch k (oldest loads), immediately refill that set
// for batch k+12, prefetch meta 16 ahead -> 24 gathers in flight, each batch's
// loads get ~2 compute phases of cover. Indices clamp to e1-1 (valid addr);
// compute guarded by e<e1. No register arrays (would go to scratch). LN fused.
#define NTAP 10
__device__ __forceinline__ float edge_msg(float b1, float b2, float dv,
                                          float a1, float a2,
                                          const __hip_bfloat16* __restrict__ Wc) {
    const float sp_ = 6.0f / 99.0f;
    const float inv_s = 99.0f / 6.0f;
    const float coeff = -0.5f * inv_s * inv_s;
    float z1 = a1 + b1, z2 = a2 + b2;
    if (dv <= 6.34f) {  // wave-uniform (dv shared across the node's lanes)
        int k0 = max(0, min(EDGE_DIM - NTAP, (int)ceilf(dv * inv_s - 4.5f)));
        const __hip_bfloat16* wr = Wc + k0 * 256;
#pragma unroll
        for (int i = 0; i < NTAP; i++) {
            float df = dv - (float)(k0 + i) * sp_;
            float ee = __expf(coeff * df * df);
            z1 = fmaf((float)wr[i * 256], ee, z1);
            z2 = fmaf((float)wr[i * 256 + 128], ee, z2);
        }
    }
    return sigmoid_f(z1) * softplus_f(z2);
}

__global__ __launch_bounds__(256) void node_edge_ln_kernel(
    const int* __restrict__ row_ptr, const int* __restrict__ s_src,
    const float* __restrict__ s_d, const float* __restrict__ P1,
    const float* __restrict__ P2, const __hip_bfloat16* __restrict__ We,
    const float* __restrict__ lg, const float* __restrict__ lb,
    float* __restrict__ x, __hip_bfloat16* __restrict__ xb) {
    int node = blockIdx.x * 2 + (threadIdx.x >> 7);
    int c = threadIdx.x & 127;
    int e0 = row_ptr[node], e1 = row_ptr[node + 1];
    float a1 = P1[(size_t)node * 256 + c];
    float a2 = P1[(size_t)node * 256 + 128 + c];
    const __hip_bfloat16* Wc = We + c;
    float acc = 0.f;

    if (e0 < e1) {
        const int emax = e1 - 1;
        // meta regs (lookahead batch) and three data sets (token-pasted names)
        int s0, s1, s2, s3;
        float m0, m1, m2, m3;
        float A10, A20, A11, A21, A12, A22, A13, A23, Ad0, Ad1, Ad2, Ad3;
        float B10, B20, B11, B21, B12, B22, B13, B23, Bd0, Bd1, Bd2, Bd3;
        float C10, C20, C11, C21, C12, C22, C13, C23, Cd0, Cd1, Cd2, Cd3;

#define META_LOAD(base_)                                                      \
        {                                                                     \
            int _e0 = min((base_),     emax); s0 = s_src[_e0]; m0 = s_d[_e0]; \
            int _e1 = min((base_) + 1, emax); s1 = s_src[_e1]; m1 = s_d[_e1]; \
            int _e2 = min((base_) + 2, emax); s2 = s_src[_e2]; m2 = s_d[_e2]; \
            int _e3 = min((base_) + 3, emax); s3 = s_src[_e3]; m3 = s_d[_e3]; \
        }
#define DATA_ISSUE(S)                                                         \
        {                                                                     \
            S##10 = P2[(size_t)s0 * 256 + c]; S##20 = P2[(size_t)s0 * 256 + 128 + c]; \
            S##11 = P2[(size_t)s1 * 256 + c]; S##21 = P2[(size_t)s1 * 256 + 128 + c]; \
            S##12 = P2[(size_t)s2 * 256 + c]; S##22 = P2[(size_t)s2 * 256 + 128 + c]; \
            S##13 = P2[(size_t)s3 * 256 + c]; S##23 = P2[(size_t)s3 * 256 + 128 + c]; \
            S##d0 = m0; S##d1 = m1; S##d2 = m2; S##d3 = m3;                   \
        }
#define COMPUTE(S, base_)                                                     \
        {                                                                     \
            if ((base_)     < e1) acc += edge_msg(S##10, S##20, S##d0, a1, a2, Wc); \
            if ((base_) + 1 < e1) acc += edge_msg(S##11, S##21, S##d1, a1, a2, Wc); \
            if ((base_) + 2 < e1) acc += edge_msg(S##12, S##22, S##d2, a1, a2, Wc); \
            if ((base_) + 3 < e1) acc += edge_msg(S##13, S##23, S##d3, a1, a2, Wc); \
        }

        // prologue: A=e0, B=e0+4, C=e0+8 issued; meta holds e0+12
        META_LOAD(e0);      DATA_ISSUE(A);
        META_LOAD(e0 + 4);  DATA_ISSUE(B);
        META_LOAD(e0 + 8);  DATA_ISSUE(C);
        META_LOAD(e0 + 12);
        int eb = e0;
        while (true) {
            COMPUTE(A, eb);
            DATA_ISSUE(A);             // refill A <- batch eb+12 (meta regs)
            META_LOAD(eb + 16);        // meta for next refill
            eb += 4; if (eb >= e1) break;

            COMPUTE(B, eb);
            DATA_ISSUE(B);
            META_LOAD(eb + 16);
            eb += 4; if (eb >= e1) break;

            COMPUTE(C, eb);
            DATA_ISSUE(C);
            META_LOAD(eb + 16);
            eb += 4; if (eb >= e1) break;
        }
#undef META_LOAD
#undef DATA_ISSUE
#undef COMPUTE
    }

    // ---- fused layernorm + residual + softplus ----
    __shared__ float sm[4][2];
    float s1r = acc, s2r = acc * acc;
#pragma unroll
    for (int off = 32; off > 0; off >>= 1) {
        s1r += __shfl_xor(s1r, off);
        s2r += __shfl_xor(s2r, off);
    }
    int wv = threadIdx.x >> 6;
    if ((threadIdx.x & 63) == 0) { sm[wv][0] = s1r; sm[wv][1] = s2r; }
    __syncthreads();
    int w0 = (threadIdx.x >> 7) * 2;
    float S1 = sm[w0][0] + sm[w0 + 1][0];
    float S2 = sm[w0][1] + sm[w0 + 1][1];
    float mu = S1 * (1.0f / 128.0f);
    float var = S2 * (1.0f / 128.0f) - mu * mu;
    float rstd = rsqrtf(fmaxf(var, 0.f) + 1e-5f);
    float xv = x[(size_t)node * 128 + c];
    float res = softplus_f((acc - mu) * rstd * lg[c] + lb[c] + xv);
    x[(size_t)node * 128 + c] = res;
    xb[(size_t)node * 128 + c] = (__hip_bfloat16)res;
}

// ---------------------------------------------------------------- fused mean-pool + MLP head
__global__ void pool_head_kernel(const float* __restrict__ x, const int* __restrict__ gs,
                                 const float* __restrict__ cfc_w, const float* __restrict__ cfc_b,
                                 const float* __restrict__ fc_w, const float* __restrict__ fc_b,
                                 const float* __restrict__ out_w, const float* __restrict__ out_b,
                                 float* __restrict__ out) {
    int g = blockIdx.x, c = threadIdx.x;  // 128 threads
    int n0 = gs[g], n1 = gs[g + 1];
    float s = 0.f;
    for (int n = n0; n < n1; n++) s += x[(size_t)n * 128 + c];
    __shared__ float h[128], h2[128];
    h[c] = s / fmaxf((float)(n1 - n0), 1.0f);
    __syncthreads();
    float acc = cfc_b[c];
    for (int k = 0; k < 128; k++) acc = fmaf(h[k], cfc_w[k * 128 + c], acc);
    h2[c] = softplus_f(acc);
    __syncthreads();
    for (int l = 0; l < 2; l++) {
        const float* W = fc_w + l * 128 * 128;
        acc = fc_b[l * 128 + c];
        for (int k = 0; k < 128; k++) acc = fmaf(h2[k], W[k * 128 + c], acc);
        __syncthreads();
        h2[c] = softplus_f(acc);
        __syncthreads();
    }
    h[c] = h2[c] * out_w[c];
    __syncthreads();
    for (int off = 64; off > 0; off >>= 1) {
        if (c < off) h[c] += h[c + off];
        __syncthreads();
    }
    if (c == 0) out[g] = h[0] + out_b[0];
}

// ---------------------------------------------------------------- launcher
extern "C" void kernel_launch(void* const* d_in, const int* in_sizes, int n_in,
                              void* d_out, int out_size, void* d_ws, size_t ws_size,
                              hipStream_t stream) {
    const int*   z      = (const int*)d_in[0];
    const float* R      = (const float*)d_in[1];
    const int*   ei     = (const int*)d_in[2];
    const int*   batch  = (const int*)d_in[3];
    const float* emb    = (const float*)d_in[4];
    const float* emb_w  = (const float*)d_in[5];
    const float* emb_b  = (const float*)d_in[6];
    const float* conv_w = (const float*)d_in[7];
    const float* conv_b = (const float*)d_in[8];
    const float* ln_g   = (const float*)d_in[9];
    const float* ln_b   = (const float*)d_in[10];
    const float* cfc_w  = (const float*)d_in[11];
    const float* cfc_b  = (const float*)d_in[12];
    const float* fc_w   = (const float*)d_in[13];
    const float* fc_b   = (const float*)d_in[14];
    const float* out_w  = (const float*)d_in[15];
    const float* out_b  = (const float*)d_in[16];
    float* out = (float*)d_out;

    float* ws    = (float*)d_ws;
    float* x     = ws;                     // 6,400,000
    float* agg   = x + 6400000;            // 6,400,000 (unused; layout kept)
    float* P1    = agg + 6400000;          // 12,800,000
    float* P2    = P1 + 12800000;          // 12,800,000
    float* s_d   = P2 + 12800000;          // 800,000
    int* s_src   = (int*)(s_d + 800000);   // 800,000
    int* s_dst   = s_src + 800000;         // 800,000 (unused; layout kept)
    int* row_ptr = s_dst + 800000;         // 50,004
    int* deg     = row_ptr + 50004;        // 50,000
    int* cnt2    = deg + 50000;            // 50,000
    int* bsum    = cnt2 + 50000;           // 64
    int* gs      = bsum + 64;              // 260
    __hip_bfloat16* Webf = (__hip_bfloat16*)(gs + 260);        // 76,800 bf16
    short* WbB           = (short*)(Webf + 76800);             // 196,608 shorts
    __hip_bfloat16* xb   = (__hip_bfloat16*)(WbB + 196608);    // 6,400,000 bf16

    hipMemsetAsync(deg, 0, (size_t)100000 * 4, stream);  // deg + cnt2
    deg_kernel<<<(N_EDGES + 255) / 256, 256, 0, stream>>>(ei, deg);
    int nsb = (N_NODES + SB - 1) / SB;  // 49
    scan1_kernel<<<nsb, SB, 0, stream>>>(deg, row_ptr, bsum);
    scan2_kernel<<<1, 64, 0, stream>>>(bsum, nsb);
    scan3_kernel<<<nsb, SB, 0, stream>>>(row_ptr, bsum);
    fill_kernel<<<(N_EDGES + 255) / 256, 256, 0, stream>>>(ei, R, row_ptr, cnt2,
                                                           s_src, s_d);
    gb_kernel<<<(N_NODES + 256) / 256 + 1, 256, 0, stream>>>(batch, gs);
    wcvt_kernel<<<(3 * EDGE_DIM * 256 + 255) / 256, 256, 0, stream>>>(conv_w, Webf);
    wprep_kernel<<<(3 * 4 * 32 * 64 * 8 + 255) / 256, 256, 0, stream>>>(conv_w, WbB);

    embed_kernel<<<N_NODES / 8, 128, 0, stream>>>(z, emb, emb_w, emb_b, x, xb);
    for (int l = 0; l < 3; l++) {
        node_mfma_kernel<<<N_NODES / 16, 256, 0, stream>>>(xb, WbB + (size_t)l * 65536,
                                                           conv_b + l * 256, P1, P2);
        node_edge_ln_kernel<<<N_NODES / 2, 256, 0, stream>>>(
            row_ptr, s_src, s_d, P1, P2, Webf + (size_t)l * EDGE_DIM * 256,
            ln_g + l * 128, ln_b + l * 128, x, xb);
    }
    pool_head_kernel<<<N_GRAPHS, 128, 0, stream>>>(x, gs, cfc_w, cfc_b, fc_w, fc_b,
                                                   out_w, out_b, out);
}